// Round 12
// baseline (84.708 us; speedup 1.0000x reference)
//
#include <hip/hip_runtime.h>
#include <math.h>

#define Bn 64
#define Pn 8732
#define Cn 21
#define NMAXn 50
#define PX 35  // ceil(Pn/256)

// ---------------- DPP wave64 reduces (VALU pipe, not LDS) -------------------
// bound_ctrl=1: invalid source lanes contribute 0. max requires operands >= 0;
// sums are sign-safe (0 is identity). Result lands in lane 63.
template <int C>
__device__ __forceinline__ float dppf(float x) {
    return __int_as_float(__builtin_amdgcn_update_dpp(0, __float_as_int(x), C, 0xf, 0xf, true));
}
template <int C>
__device__ __forceinline__ int dppi(int x) {
    return __builtin_amdgcn_update_dpp(0, x, C, 0xf, 0xf, true);
}
__device__ __forceinline__ float wave_max_f(float x) {  // x >= 0
    x = fmaxf(x, dppf<0x111>(x)); x = fmaxf(x, dppf<0x112>(x));
    x = fmaxf(x, dppf<0x114>(x)); x = fmaxf(x, dppf<0x118>(x));
    x = fmaxf(x, dppf<0x142>(x)); x = fmaxf(x, dppf<0x143>(x));
    return x;
}
__device__ __forceinline__ float wave_sum_f(float x) {
    x += dppf<0x111>(x); x += dppf<0x112>(x); x += dppf<0x114>(x);
    x += dppf<0x118>(x); x += dppf<0x142>(x); x += dppf<0x143>(x);
    return x;
}
__device__ __forceinline__ int wave_sum_i(int x) {
    x += dppi<0x111>(x); x += dppi<0x112>(x); x += dppi<0x114>(x);
    x += dppi<0x118>(x); x += dppi<0x142>(x); x += dppi<0x143>(x);
    return x;
}

__device__ __forceinline__ float smoothl1_enc(const float4 l, const float4 pr,
                                              float gx0, float gy0, float gx1, float gy1) {
    const float tx = ((gx0 + gx1) * 0.5f - pr.x) / (0.1f * pr.z);
    const float ty = ((gy0 + gy1) * 0.5f - pr.y) / (0.1f * pr.w);
    const float tw = __logf((gx1 - gx0) / pr.z) * 5.0f;  // /0.2
    const float th = __logf((gy1 - gy0) / pr.w) * 5.0f;
    float s = 0.0f, d;
    d = fabsf(l.x - tx); s += (d < 1.0f) ? 0.5f * d * d : d - 0.5f;
    d = fabsf(l.y - ty); s += (d < 1.0f) ? 0.5f * d * d : d - 0.5f;
    d = fabsf(l.z - tw); s += (d < 1.0f) ? 0.5f * d * d : d - 0.5f;
    d = fabsf(l.w - th); s += (d < 1.0f) ? 0.5f * d * d : d - 0.5f;
    return s;
}

// ---------------------------------------------------------------------------
// K1 fused = old k_bpp + k_main. Per block (px,b):
//  - issue conf-tile + labels staging loads (latency hides under phase A)
//  - phase A: per-prior best-GT argmax in registers; per-(GT,wave) winner keys
//    to bpk via PLAIN stores (no atomics)
//  - main body: lse/nll from LDS tile using the LOCAL (unforced) match already
//    in registers; smooth-L1 for positives; mining score lc; DPP partials.
// match[] array no longer exists. Forced overrides = delta fixup in K2.
// ---------------------------------------------------------------------------
__global__ __launch_bounds__(256) void k_fused(const float* __restrict__ conf,
                                               const float* __restrict__ loc,
                                               const float* __restrict__ priors,
                                               const float* __restrict__ labels,
                                               const int* __restrict__ objc,
                                               float* __restrict__ lc,
                                               float* __restrict__ part_loc,
                                               float* __restrict__ part_nll,
                                               int* __restrict__ part_np,
                                               unsigned long long* __restrict__ bpk) {
    const int b = blockIdx.y;
    const int px = blockIdx.x;
    const int p0 = px * 256;
    const int tid = threadIdx.x;
    const int lane = tid & 63, wid = tid >> 6;
    const int rows = min(256, Pn - p0);
    const int cnt = objc[b];                    // uniform -> scalar
    const float* lb = labels + b * NMAXn * 5;   // uniform base -> s_loads

    __shared__ float sconf[256 * Cn];           // 21504 B
    __shared__ float lab[NMAXn * 5];
    __shared__ float rl[4], rn[4];
    __shared__ int rp[4];

    // stage conf tile + labels (issue now, consume after phase A)
    const float4* src = reinterpret_cast<const float4*>(conf + ((size_t)b * Pn + p0) * Cn);
    const int n4 = rows * Cn / 4;  // rows*21 divisible by 4 for rows in {256,28}
    for (int i = tid; i < n4; i += 256) reinterpret_cast<float4*>(sconf)[i] = src[i];
    for (int i = tid; i < NMAXn * 5; i += 256) lab[i] = labels[b * NMAXn * 5 + i];

    // ---- phase A: best-GT argmax + per-(GT,wave) best-prior keys ----
    const int p = p0 + tid;
    const bool valid = p < Pn;
    const int pcl = valid ? p : (Pn - 1);
    const float4 pr = reinterpret_cast<const float4*>(priors)[pcl];
    const float px0 = pr.x - 0.5f * pr.z, py0 = pr.y - 0.5f * pr.w;
    const float px1 = pr.x + 0.5f * pr.z, py1 = pr.y + 0.5f * pr.w;
    const float parea = (px1 - px0) * (py1 - py0);
    float best = -1.0f;
    int bidx = 0;
    for (int n = 0; n < cnt; ++n) {
        const float gx0 = lb[n * 5 + 0], gy0 = lb[n * 5 + 1];
        const float gx1 = lb[n * 5 + 2], gy1 = lb[n * 5 + 3];
        const float lx = fmaxf(gx0, px0), ly = fmaxf(gy0, py0);
        const float rx = fminf(gx1, px1), ry = fminf(gy1, py1);
        const float w = fmaxf(rx - lx, 0.0f), h = fmaxf(ry - ly, 0.0f);
        const float inter = w * h;
        const float ga = (gx1 - gx0) * (gy1 - gy0);
        const float q = inter / (ga + parea - inter);  // exact IEEE == reference
        if (q > best) { best = q; bidx = n; }          // strict >: first occurrence
        const float qr = valid ? q : 0.0f;             // reduce domain >= 0
        const float m = wave_max_f(qr);
        const float s_q = __int_as_float(__builtin_amdgcn_readlane(__float_as_int(m), 63));
        const unsigned long long mask = __ballot(qr == s_q);
        if (lane == 0) {
            const int first = __ffsll(mask) - 1;       // lowest lane == min p
            const int pw = p0 + (wid << 6) + first;
            const unsigned long long key =
                ((unsigned long long)__float_as_uint(s_q) << 32) |
                (unsigned long long)(65535 - pw);      // bigger = better (q, then min p)
            bpk[(size_t)(b * NMAXn + n) * (PX * 4) + px * 4 + wid] = key;
        }
    }
    __syncthreads();  // sconf, lab ready

    // ---- main body (local, unforced match in registers) ----
    float my_loc = 0.0f, my_nll = 0.0f;
    int my_np = 0;
    if (tid < rows) {
        const size_t gi = (size_t)b * Pn + p;
        const int ct = (best >= 0.5f) ? ((int)lab[bidx * 5 + 4] + 1) : 0;
        const float* row = sconf + tid * Cn;  // stride 21: odd -> conflict-benign
        float m = row[0];
#pragma unroll
        for (int j = 1; j < Cn; ++j) m = fmaxf(m, row[j]);
        float s2 = 0.0f;
#pragma unroll
        for (int j = 0; j < Cn; ++j) s2 += __expf(row[j] - m);
        const float nll = __logf(s2) + m - row[ct];
        if (ct > 0) {
            lc[gi] = 0.0f;
            my_np = 1;
            my_nll = nll;
            const float4 l = reinterpret_cast<const float4*>(loc)[gi];
            my_loc = smoothl1_enc(l, pr, lab[bidx * 5 + 0], lab[bidx * 5 + 1],
                                  lab[bidx * 5 + 2], lab[bidx * 5 + 3]);
        } else {
            lc[gi] = nll;
        }
    }
    my_loc = wave_sum_f(my_loc);
    my_nll = wave_sum_f(my_nll);
    my_np = wave_sum_i(my_np);
    if (lane == 63) { rl[wid] = my_loc; rn[wid] = my_nll; rp[wid] = my_np; }
    __syncthreads();
    if (tid == 0) {
        const int g = b * PX + px;
        part_loc[g] = rl[0] + rl[1] + rl[2] + rl[3];
        part_nll[g] = rn[0] + rn[1] + rn[2] + rn[3];
        part_np[g] = rp[0] + rp[1] + rp[2] + rp[3];
    }
}

// ---------------------------------------------------------------------------
// K2 fixup (one wave per batch): decode per-GT winners from bpk (max of 140
// keys), last-n-wins; for each winning forced (n -> pp): recompute the OLD
// local contribution of prior pp bitwise-identically, compute deltas
// (nll/loc/np), write lc[pp]=0 (forced => positive). R10 verified this math.
// Block 0 resets k_neg's done counter.
// ---------------------------------------------------------------------------
__global__ __launch_bounds__(64) void k_fix(const float* __restrict__ conf,
                                            const float* __restrict__ loc,
                                            const float* __restrict__ priors,
                                            const float* __restrict__ labels,
                                            const int* __restrict__ objc,
                                            const unsigned long long* __restrict__ bpk,
                                            float* __restrict__ lc,
                                            int* __restrict__ fix_np,
                                            float* __restrict__ fix_nll,
                                            float* __restrict__ fix_loc,
                                            int* __restrict__ done) {
    __shared__ int sbp[NMAXn];
    __shared__ float lab[NMAXn * 5];
    const int b = blockIdx.x;
    const int tid = threadIdx.x;  // 64 threads = exactly one wave
    if (b == 0 && tid == 0) *done = 0;
    const int cnt = objc[b];
    for (int i = tid; i < NMAXn * 5; i += 64) lab[i] = labels[b * NMAXn * 5 + i];
    if (tid < cnt) {
        const size_t g0 = (size_t)(b * NMAXn + tid) * (PX * 4);
        unsigned long long bestk = 0ull;
        for (int t = 0; t < PX * 4; ++t) {
            const unsigned long long k = bpk[g0 + t];
            bestk = (k > bestk) ? k : bestk;
        }
        sbp[tid] = 65535 - (int)(bestk & 0xFFFFull);
    }
    __syncthreads();
    bool win = false;
    if (tid < cnt) {
        const int myp = sbp[tid];
        win = true;
        for (int n2 = tid + 1; n2 < cnt; ++n2) win = win && (sbp[n2] != myp);  // last n wins
    }
    float dnll = 0.0f, dloc = 0.0f;
    int dnp = 0;
    if (win) {
        const int pp = sbp[tid];
        // recompute the OLD (unforced) match for prior pp — identical FP sequence
        const float4 prf = reinterpret_cast<const float4*>(priors)[pp];
        const float qx0 = prf.x - 0.5f * prf.z, qy0 = prf.y - 0.5f * prf.w;
        const float qx1 = prf.x + 0.5f * prf.z, qy1 = prf.y + 0.5f * prf.w;
        const float qarea = (qx1 - qx0) * (qy1 - qy0);
        float best2 = -1.0f;
        int bidx2 = 0;
        for (int n2 = 0; n2 < cnt; ++n2) {
            const float gx0 = lab[n2 * 5 + 0], gy0 = lab[n2 * 5 + 1];
            const float gx1 = lab[n2 * 5 + 2], gy1 = lab[n2 * 5 + 3];
            const float lx = fmaxf(gx0, qx0), ly = fmaxf(gy0, qy0);
            const float rx = fminf(gx1, qx1), ry = fminf(gy1, qy1);
            const float w = fmaxf(rx - lx, 0.0f), h = fmaxf(ry - ly, 0.0f);
            const float inter = w * h;
            const float ga = (gx1 - gx0) * (gy1 - gy0);
            const float q = inter / (ga + qarea - inter);
            if (q > best2) { best2 = q; bidx2 = n2; }
        }
        const float* rowg = conf + ((size_t)b * Pn + pp) * Cn;
        float m2 = rowg[0];
#pragma unroll
        for (int j = 1; j < Cn; ++j) m2 = fmaxf(m2, rowg[j]);
        float ss = 0.0f;
#pragma unroll
        for (int j = 0; j < Cn; ++j) ss += __expf(rowg[j] - m2);
        const float lse = __logf(ss) + m2;
        const int ctn = (int)lab[tid * 5 + 4] + 1;     // forced class (always positive)
        const float4 lv = reinterpret_cast<const float4*>(loc)[(size_t)b * Pn + pp];
        dnll = lse - rowg[ctn];
        dloc = smoothl1_enc(lv, prf, lab[tid * 5 + 0], lab[tid * 5 + 1],
                            lab[tid * 5 + 2], lab[tid * 5 + 3]);
        dnp = 1;
        if (best2 >= 0.5f) {  // old was positive: subtract its old contribution
            const int cto = (int)lab[bidx2 * 5 + 4] + 1;
            dnll -= (lse - rowg[cto]);
            dloc -= smoothl1_enc(lv, prf, lab[bidx2 * 5 + 0], lab[bidx2 * 5 + 1],
                                 lab[bidx2 * 5 + 2], lab[bidx2 * 5 + 3]);
            dnp = 0;
        }
        lc[(size_t)b * Pn + pp] = 0.0f;  // forced => positive => not a mining candidate
    }
    dnll = wave_sum_f(dnll);
    dloc = wave_sum_f(dloc);
    dnp = wave_sum_i(dnp);
    if (tid == 63) {
        fix_nll[b] = dnll;
        fix_loc[b] = dloc;
        fix_np[b] = dnp;
    }
}

// ---------------------------------------------------------------------------
// K3: per-batch hard-negative top-k sum. 256 threads x 12 float4 in registers
// (fully unrolled); 31-iter bisection on float bits (exact); DPP reduces with
// 4-slot LDS combine; fused final reduce (adds fix_* deltas) via done counter.
// ---------------------------------------------------------------------------
__global__ __launch_bounds__(256) void k_neg(const float* __restrict__ lc,
                                             const float* __restrict__ part_loc,
                                             const float* __restrict__ part_nll,
                                             const int* __restrict__ part_np,
                                             const int* __restrict__ fix_np,
                                             const float* __restrict__ fix_nll,
                                             const float* __restrict__ fix_loc,
                                             float* __restrict__ negsum,
                                             int* __restrict__ done,
                                             float* __restrict__ out) {
    const int b = blockIdx.x;
    const int tid = threadIdx.x;
    const int lane = tid & 63, wid = tid >> 6;
    __shared__ int redc[2][4];
    __shared__ float redf[4], redf2[4];
    __shared__ int redi[4];
    __shared__ int np_sh, islast;

    const int NV = Pn / 4;  // 2183 float4s exactly
    const float4* src = reinterpret_cast<const float4*>(lc + (size_t)b * Pn);
    const float4 sent = make_float4(-1.0f, -1.0f, -1.0f, -1.0f);
    float4 rr[12];
#pragma unroll
    for (int j = 0; j < 12; ++j) {
        const int i = tid + 256 * j;
        rr[j] = (i < NV) ? src[i] : sent;
    }

    if (tid < 64) {
        int npl = (tid < PX) ? part_np[b * PX + tid] : 0;
        npl = wave_sum_i(npl);
        if (tid == 63) np_sh = npl;
    }
    __syncthreads();
    const int k = min(3 * (np_sh + fix_np[b]), Pn - 1);

    unsigned lo = 0u, hi = 0x7F800000u;
#pragma unroll 1
    for (int it = 0; it < 31; ++it) {
        const unsigned mid = lo + ((hi - lo) >> 1);
        const float fm = __uint_as_float(mid);  // fm >= 0: sentinels never counted
        int c = 0;
#pragma unroll
        for (int j = 0; j < 12; ++j)
            c += (rr[j].x >= fm) + (rr[j].y >= fm) + (rr[j].z >= fm) + (rr[j].w >= fm);
        c = wave_sum_i(c);
        if (lane == 63) redc[it & 1][wid] = c;
        __syncthreads();
        const int tot = redc[it & 1][0] + redc[it & 1][1]
                      + redc[it & 1][2] + redc[it & 1][3];
        if (tot >= k) lo = mid;
        else hi = mid;
    }
    const float v = __uint_as_float(lo);  // exact k-th largest value

    float sm = 0.0f;
    int c = 0;
#pragma unroll
    for (int j = 0; j < 12; ++j) {
        if (rr[j].x > v) { sm += rr[j].x; ++c; }
        if (rr[j].y > v) { sm += rr[j].y; ++c; }
        if (rr[j].z > v) { sm += rr[j].z; ++c; }
        if (rr[j].w > v) { sm += rr[j].w; ++c; }
    }
    sm = wave_sum_f(sm);
    c = wave_sum_i(c);
    if (lane == 63) { redf[wid] = sm; redi[wid] = c; }
    __syncthreads();
    if (tid == 0) {
        const float st = redf[0] + redf[1] + redf[2] + redf[3];
        const int ct = redi[0] + redi[1] + redi[2] + redi[3];
        negsum[b] = st + (float)(k - ct) * v;  // exact tie handling at boundary
        __threadfence();
        islast = (atomicAdd(done, 1) == Bn - 1) ? 1 : 0;
    }
    __syncthreads();
    if (!islast) return;
    __threadfence();  // acquire: other blocks' stores precede their fenced atomics

    // ---- fused final reduce (exactly one block runs this) ----
    float sl = 0.0f, sn = 0.0f;
    int np = 0;
    for (int i = tid; i < Bn * PX; i += 256) {
        sl += part_loc[i];
        sn += part_nll[i];
        np += part_np[i];
    }
    if (tid < Bn) {
        sn += negsum[tid] + fix_nll[tid];
        sl += fix_loc[tid];
        np += fix_np[tid];
    }
    sl = wave_sum_f(sl);
    sn = wave_sum_f(sn);
    np = wave_sum_i(np);
    if (lane == 63) { redf[wid] = sn; redf2[wid] = sl; redi[wid] = np; }
    __syncthreads();
    if (tid == 0) {
        const float fN = (float)(redi[0] + redi[1] + redi[2] + redi[3]);
        out[0] = (redf2[0] + redf2[1] + redf2[2] + redf2[3]) / fN;
        out[1] = (redf[0] + redf[1] + redf[2] + redf[3]) / fN;
    }
}

extern "C" void kernel_launch(void* const* d_in, const int* in_sizes, int n_in,
                              void* d_out, int out_size, void* d_ws, size_t ws_size,
                              hipStream_t stream) {
    const float* conf = (const float*)d_in[0];
    const float* loc = (const float*)d_in[1];
    const float* priors = (const float*)d_in[2];
    const float* labels = (const float*)d_in[3];
    const int* objc = (const int*)d_in[4];
    float* out = (float*)d_out;

    // ws layout: bpk[Bn*NMAXn*140] u64 | part_loc/nll/np[2240 each] | negsum[64] |
    //            fix_np[64] | fix_nll[64] | fix_loc[64] | lc[Bn*Pn] | done
    unsigned long long* bpk = (unsigned long long*)d_ws;          // 3.584 MB
    float* part_loc = (float*)(bpk + (size_t)Bn * NMAXn * PX * 4);
    float* part_nll = part_loc + Bn * PX;
    int* part_np = (int*)(part_nll + Bn * PX);
    float* negsum = (float*)(part_np + Bn * PX);
    int* fix_np = (int*)(negsum + Bn);
    float* fix_nll = (float*)(fix_np + Bn);
    float* fix_loc = fix_nll + Bn;
    float* lc = fix_loc + Bn;
    int* done = (int*)(lc + (size_t)Bn * Pn);

    dim3 g(PX, Bn);
    k_fused<<<g, 256, 0, stream>>>(conf, loc, priors, labels, objc, lc,
                                   part_loc, part_nll, part_np, bpk);
    k_fix<<<Bn, 64, 0, stream>>>(conf, loc, priors, labels, objc, bpk, lc,
                                 fix_np, fix_nll, fix_loc, done);
    k_neg<<<Bn, 256, 0, stream>>>(lc, part_loc, part_nll, part_np,
                                  fix_np, fix_nll, fix_loc, negsum, done, out);
}

// Round 13
// 75.725 us; speedup vs baseline: 1.1186x; 1.1186x over previous
//
#include <hip/hip_runtime.h>
#include <math.h>

#define Bn 64
#define Pn 8732
#define Cn 21
#define NMAXn 50
#define PX 35  // ceil(Pn/256)

// ---------------- DPP wave64 reduces (VALU pipe, not LDS) -------------------
template <int C>
__device__ __forceinline__ float dppf(float x) {
    return __int_as_float(__builtin_amdgcn_update_dpp(0, __float_as_int(x), C, 0xf, 0xf, true));
}
template <int C>
__device__ __forceinline__ int dppi(int x) {
    return __builtin_amdgcn_update_dpp(0, x, C, 0xf, 0xf, true);
}
__device__ __forceinline__ float wave_sum_f(float x) {
    x += dppf<0x111>(x); x += dppf<0x112>(x); x += dppf<0x114>(x);
    x += dppf<0x118>(x); x += dppf<0x142>(x); x += dppf<0x143>(x);
    return x;  // lane 63
}
__device__ __forceinline__ int wave_sum_i(int x) {
    x += dppi<0x111>(x); x += dppi<0x112>(x); x += dppi<0x114>(x);
    x += dppi<0x118>(x); x += dppi<0x142>(x); x += dppi<0x143>(x);
    return x;  // lane 63
}

__device__ __forceinline__ float smoothl1_enc(const float4 l, const float4 pr,
                                              float gx0, float gy0, float gx1, float gy1) {
    const float tx = ((gx0 + gx1) * 0.5f - pr.x) / (0.1f * pr.z);
    const float ty = ((gy0 + gy1) * 0.5f - pr.y) / (0.1f * pr.w);
    const float tw = __logf((gx1 - gx0) / pr.z) * 5.0f;  // /0.2
    const float th = __logf((gy1 - gy0) / pr.w) * 5.0f;
    float s = 0.0f, d;
    d = fabsf(l.x - tx); s += (d < 1.0f) ? 0.5f * d * d : d - 0.5f;
    d = fabsf(l.y - ty); s += (d < 1.0f) ? 0.5f * d * d : d - 0.5f;
    d = fabsf(l.z - tw); s += (d < 1.0f) ? 0.5f * d * d : d - 0.5f;
    d = fabsf(l.w - th); s += (d < 1.0f) ? 0.5f * d * d : d - 0.5f;
    return s;
}

// ---------------------------------------------------------------------------
// K1, two roles in one dispatch (5440 blocks):
//  Role A (bx < Bn*PX): per-prior best-GT argmax — PURE per-thread loop, zero
//    cross-lane ops — fused with the main body (lse/nll/smooth-L1/lc/partials).
//  Role B (bx >= Bn*PX): block-per-(b,n) best-prior argmax over all priors;
//    per-thread tracker over ~35 strided priors, ONE u64-key reduce at the
//    end; writes the global winner sbp_g[b][n]. Key = q_bits<<32 | (65535-p)
//    -> max = (max q, then min p) = reference first-occurrence argmax.
// ---------------------------------------------------------------------------
__global__ __launch_bounds__(256) void k_fused(const float* __restrict__ conf,
                                               const float* __restrict__ loc,
                                               const float* __restrict__ priors,
                                               const float* __restrict__ labels,
                                               const int* __restrict__ objc,
                                               float* __restrict__ lc,
                                               float* __restrict__ part_loc,
                                               float* __restrict__ part_nll,
                                               int* __restrict__ part_np,
                                               int* __restrict__ sbp_g) {
    const int bx = blockIdx.x;
    const int tid = threadIdx.x;
    const int lane = tid & 63, wid = tid >> 6;

    __shared__ float sconf[256 * Cn];  // 21504 B (role A)
    __shared__ float lab[NMAXn * 5];
    __shared__ float rl[4], rn[4];
    __shared__ int rp[4];
    __shared__ unsigned long long wk[4];  // role B

    if (bx < Bn * PX) {
        // ================= Role A: match + main =================
        const int b = bx / PX;
        const int px = bx % PX;
        const int p0 = px * 256;
        const int rows = min(256, Pn - p0);
        const int cnt = objc[b];                  // uniform -> scalar
        const float* lb = labels + b * NMAXn * 5;

        const float4* src = reinterpret_cast<const float4*>(conf + ((size_t)b * Pn + p0) * Cn);
        const int n4 = rows * Cn / 4;  // rows*21 divisible by 4 for rows in {256,28}
        for (int i = tid; i < n4; i += 256) reinterpret_cast<float4*>(sconf)[i] = src[i];
        for (int i = tid; i < NMAXn * 5; i += 256) lab[i] = labels[b * NMAXn * 5 + i];

        const int p = p0 + tid;
        const bool valid = p < Pn;
        const int pcl = valid ? p : (Pn - 1);
        const float4 pr = reinterpret_cast<const float4*>(priors)[pcl];
        const float px0 = pr.x - 0.5f * pr.z, py0 = pr.y - 0.5f * pr.w;
        const float px1 = pr.x + 0.5f * pr.z, py1 = pr.y + 0.5f * pr.w;
        const float parea = (px1 - px0) * (py1 - py0);
        float best = -1.0f;
        int bidx = 0;
        for (int n = 0; n < cnt; ++n) {   // pure per-thread: no cross-lane ops
            const float gx0 = lb[n * 5 + 0], gy0 = lb[n * 5 + 1];
            const float gx1 = lb[n * 5 + 2], gy1 = lb[n * 5 + 3];
            const float lx = fmaxf(gx0, px0), ly = fmaxf(gy0, py0);
            const float rx = fminf(gx1, px1), ry = fminf(gy1, py1);
            const float w = fmaxf(rx - lx, 0.0f), h = fmaxf(ry - ly, 0.0f);
            const float inter = w * h;
            const float ga = (gx1 - gx0) * (gy1 - gy0);
            const float q = inter / (ga + parea - inter);  // exact IEEE == reference
            if (q > best) { best = q; bidx = n; }          // strict >: first occurrence
        }
        __syncthreads();  // sconf, lab ready

        float my_loc = 0.0f, my_nll = 0.0f;
        int my_np = 0;
        if (tid < rows) {
            const size_t gi = (size_t)b * Pn + p;
            const int ct = (best >= 0.5f) ? ((int)lab[bidx * 5 + 4] + 1) : 0;
            const float* row = sconf + tid * Cn;  // stride 21: odd -> conflict-benign
            float m = row[0];
#pragma unroll
            for (int j = 1; j < Cn; ++j) m = fmaxf(m, row[j]);
            float s2 = 0.0f;
#pragma unroll
            for (int j = 0; j < Cn; ++j) s2 += __expf(row[j] - m);
            const float nll = __logf(s2) + m - row[ct];
            if (ct > 0) {
                lc[gi] = 0.0f;
                my_np = 1;
                my_nll = nll;
                const float4 l = reinterpret_cast<const float4*>(loc)[gi];
                my_loc = smoothl1_enc(l, pr, lab[bidx * 5 + 0], lab[bidx * 5 + 1],
                                      lab[bidx * 5 + 2], lab[bidx * 5 + 3]);
            } else {
                lc[gi] = nll;
            }
        }
        my_loc = wave_sum_f(my_loc);
        my_nll = wave_sum_f(my_nll);
        my_np = wave_sum_i(my_np);
        if (lane == 63) { rl[wid] = my_loc; rn[wid] = my_nll; rp[wid] = my_np; }
        __syncthreads();
        if (tid == 0) {
            const int g = b * PX + px;
            part_loc[g] = rl[0] + rl[1] + rl[2] + rl[3];
            part_nll[g] = rn[0] + rn[1] + rn[2] + rn[3];
            part_np[g] = rp[0] + rp[1] + rp[2] + rp[3];
        }
    } else {
        // ================= Role B: block-per-GT best-prior =================
        const int idx = bx - Bn * PX;
        const int b = idx / NMAXn;
        const int n = idx % NMAXn;
        if (n >= objc[b]) return;  // uniform per block
        const float* lbp = labels + (b * NMAXn + n) * 5;
        const float gx0 = lbp[0], gy0 = lbp[1], gx1 = lbp[2], gy1 = lbp[3];
        const float ga = (gx1 - gx0) * (gy1 - gy0);
        float bq = -1.0f;
        int bp_ = 0;
        for (int j = 0; j < PX; ++j) {           // ascending j: in-thread min p kept
            const int p = tid + 256 * j;         // coalesced float4 across lanes
            if (p < Pn) {
                const float4 pr = reinterpret_cast<const float4*>(priors)[p];
                const float px0 = pr.x - 0.5f * pr.z, py0 = pr.y - 0.5f * pr.w;
                const float px1 = pr.x + 0.5f * pr.z, py1 = pr.y + 0.5f * pr.w;
                const float lx = fmaxf(gx0, px0), ly = fmaxf(gy0, py0);
                const float rx = fminf(gx1, px1), ry = fminf(gy1, py1);
                const float w = fmaxf(rx - lx, 0.0f), h = fmaxf(ry - ly, 0.0f);
                const float inter = w * h;
                const float pa = (px1 - px0) * (py1 - py0);
                const float q = inter / (ga + pa - inter);  // exact IEEE
                if (q > bq) { bq = q; bp_ = p; }
            }
        }
        // ONE reduce: u64 key = (q_bits << 32) | (65535 - p); max == (q, min p)
        unsigned long long key = ((unsigned long long)__float_as_uint(bq) << 32) |
                                 (unsigned long long)(65535 - bp_);
        for (int off = 32; off > 0; off >>= 1) {
            const unsigned long long o = __shfl_down(key, off);
            key = (o > key) ? o : key;
        }
        if (lane == 0) wk[wid] = key;
        __syncthreads();
        if (tid == 0) {
            unsigned long long kk = wk[0];
            kk = (wk[1] > kk) ? wk[1] : kk;
            kk = (wk[2] > kk) ? wk[2] : kk;
            kk = (wk[3] > kk) ? wk[3] : kk;
            sbp_g[b * NMAXn + n] = 65535 - (int)(kk & 0xFFFFull);
        }
    }
}

// ---------------------------------------------------------------------------
// K2 fixup (one wave per batch): stage sbp from global; last-n-wins; for each
// winning forced (n -> pp): recompute the OLD local contribution bitwise-
// identically, emit deltas (nll/loc/np), write lc[pp]=0. Resets done counter.
// ---------------------------------------------------------------------------
__global__ __launch_bounds__(64) void k_fix(const float* __restrict__ conf,
                                            const float* __restrict__ loc,
                                            const float* __restrict__ priors,
                                            const float* __restrict__ labels,
                                            const int* __restrict__ objc,
                                            const int* __restrict__ sbp_g,
                                            float* __restrict__ lc,
                                            int* __restrict__ fix_np,
                                            float* __restrict__ fix_nll,
                                            float* __restrict__ fix_loc,
                                            int* __restrict__ done) {
    __shared__ int sbp[NMAXn];
    __shared__ float lab[NMAXn * 5];
    const int b = blockIdx.x;
    const int tid = threadIdx.x;  // one wave
    if (b == 0 && tid == 0) *done = 0;
    const int cnt = objc[b];
    for (int i = tid; i < NMAXn * 5; i += 64) lab[i] = labels[b * NMAXn * 5 + i];
    if (tid < cnt) sbp[tid] = sbp_g[b * NMAXn + tid];
    __syncthreads();
    bool win = false;
    if (tid < cnt) {
        const int myp = sbp[tid];
        win = true;
        for (int n2 = tid + 1; n2 < cnt; ++n2) win = win && (sbp[n2] != myp);  // last n wins
    }
    float dnll = 0.0f, dloc = 0.0f;
    int dnp = 0;
    if (win) {
        const int pp = sbp[tid];
        const float4 prf = reinterpret_cast<const float4*>(priors)[pp];
        const float qx0 = prf.x - 0.5f * prf.z, qy0 = prf.y - 0.5f * prf.w;
        const float qx1 = prf.x + 0.5f * prf.z, qy1 = prf.y + 0.5f * prf.w;
        const float qarea = (qx1 - qx0) * (qy1 - qy0);
        float best2 = -1.0f;
        int bidx2 = 0;
        for (int n2 = 0; n2 < cnt; ++n2) {
            const float gx0 = lab[n2 * 5 + 0], gy0 = lab[n2 * 5 + 1];
            const float gx1 = lab[n2 * 5 + 2], gy1 = lab[n2 * 5 + 3];
            const float lx = fmaxf(gx0, qx0), ly = fmaxf(gy0, qy0);
            const float rx = fminf(gx1, qx1), ry = fminf(gy1, qy1);
            const float w = fmaxf(rx - lx, 0.0f), h = fmaxf(ry - ly, 0.0f);
            const float inter = w * h;
            const float ga = (gx1 - gx0) * (gy1 - gy0);
            const float q = inter / (ga + qarea - inter);
            if (q > best2) { best2 = q; bidx2 = n2; }
        }
        const float* rowg = conf + ((size_t)b * Pn + pp) * Cn;
        float m2 = rowg[0];
#pragma unroll
        for (int j = 1; j < Cn; ++j) m2 = fmaxf(m2, rowg[j]);
        float ss = 0.0f;
#pragma unroll
        for (int j = 0; j < Cn; ++j) ss += __expf(rowg[j] - m2);
        const float lse = __logf(ss) + m2;
        const int ctn = (int)lab[tid * 5 + 4] + 1;
        const float4 lv = reinterpret_cast<const float4*>(loc)[(size_t)b * Pn + pp];
        dnll = lse - rowg[ctn];
        dloc = smoothl1_enc(lv, prf, lab[tid * 5 + 0], lab[tid * 5 + 1],
                            lab[tid * 5 + 2], lab[tid * 5 + 3]);
        dnp = 1;
        if (best2 >= 0.5f) {
            const int cto = (int)lab[bidx2 * 5 + 4] + 1;
            dnll -= (lse - rowg[cto]);
            dloc -= smoothl1_enc(lv, prf, lab[bidx2 * 5 + 0], lab[bidx2 * 5 + 1],
                                 lab[bidx2 * 5 + 2], lab[bidx2 * 5 + 3]);
            dnp = 0;
        }
        lc[(size_t)b * Pn + pp] = 0.0f;  // forced => positive => not a mining candidate
    }
    dnll = wave_sum_f(dnll);
    dloc = wave_sum_f(dloc);
    dnp = wave_sum_i(dnp);
    if (tid == 63) {
        fix_nll[b] = dnll;
        fix_loc[b] = dloc;
        fix_np[b] = dnp;
    }
}

// ---------------------------------------------------------------------------
// K3: per-batch hard-negative top-k sum. 256 threads x 12 float4 in registers;
// 31-iter bisection on float bits (exact); DPP reduces + 4-slot LDS combine;
// fused final reduce (adds fix_* deltas) via done counter.
// ---------------------------------------------------------------------------
__global__ __launch_bounds__(256) void k_neg(const float* __restrict__ lc,
                                             const float* __restrict__ part_loc,
                                             const float* __restrict__ part_nll,
                                             const int* __restrict__ part_np,
                                             const int* __restrict__ fix_np,
                                             const float* __restrict__ fix_nll,
                                             const float* __restrict__ fix_loc,
                                             float* __restrict__ negsum,
                                             int* __restrict__ done,
                                             float* __restrict__ out) {
    const int b = blockIdx.x;
    const int tid = threadIdx.x;
    const int lane = tid & 63, wid = tid >> 6;
    __shared__ int redc[2][4];
    __shared__ float redf[4], redf2[4];
    __shared__ int redi[4];
    __shared__ int np_sh, islast;

    const int NV = Pn / 4;  // 2183 float4s exactly
    const float4* src = reinterpret_cast<const float4*>(lc + (size_t)b * Pn);
    const float4 sent = make_float4(-1.0f, -1.0f, -1.0f, -1.0f);
    float4 rr[12];
#pragma unroll
    for (int j = 0; j < 12; ++j) {
        const int i = tid + 256 * j;
        rr[j] = (i < NV) ? src[i] : sent;
    }

    if (tid < 64) {
        int npl = (tid < PX) ? part_np[b * PX + tid] : 0;
        npl = wave_sum_i(npl);
        if (tid == 63) np_sh = npl;
    }
    __syncthreads();
    const int k = min(3 * (np_sh + fix_np[b]), Pn - 1);

    unsigned lo = 0u, hi = 0x7F800000u;
#pragma unroll 1
    for (int it = 0; it < 31; ++it) {
        const unsigned mid = lo + ((hi - lo) >> 1);
        const float fm = __uint_as_float(mid);  // fm >= 0: sentinels never counted
        int c = 0;
#pragma unroll
        for (int j = 0; j < 12; ++j)
            c += (rr[j].x >= fm) + (rr[j].y >= fm) + (rr[j].z >= fm) + (rr[j].w >= fm);
        c = wave_sum_i(c);
        if (lane == 63) redc[it & 1][wid] = c;
        __syncthreads();
        const int tot = redc[it & 1][0] + redc[it & 1][1]
                      + redc[it & 1][2] + redc[it & 1][3];
        if (tot >= k) lo = mid;
        else hi = mid;
    }
    const float v = __uint_as_float(lo);  // exact k-th largest value

    float sm = 0.0f;
    int c = 0;
#pragma unroll
    for (int j = 0; j < 12; ++j) {
        if (rr[j].x > v) { sm += rr[j].x; ++c; }
        if (rr[j].y > v) { sm += rr[j].y; ++c; }
        if (rr[j].z > v) { sm += rr[j].z; ++c; }
        if (rr[j].w > v) { sm += rr[j].w; ++c; }
    }
    sm = wave_sum_f(sm);
    c = wave_sum_i(c);
    if (lane == 63) { redf[wid] = sm; redi[wid] = c; }
    __syncthreads();
    if (tid == 0) {
        const float st = redf[0] + redf[1] + redf[2] + redf[3];
        const int ct = redi[0] + redi[1] + redi[2] + redi[3];
        negsum[b] = st + (float)(k - ct) * v;  // exact tie handling at boundary
        __threadfence();
        islast = (atomicAdd(done, 1) == Bn - 1) ? 1 : 0;
    }
    __syncthreads();
    if (!islast) return;
    __threadfence();

    float sl = 0.0f, sn = 0.0f;
    int np = 0;
    for (int i = tid; i < Bn * PX; i += 256) {
        sl += part_loc[i];
        sn += part_nll[i];
        np += part_np[i];
    }
    if (tid < Bn) {
        sn += negsum[tid] + fix_nll[tid];
        sl += fix_loc[tid];
        np += fix_np[tid];
    }
    sl = wave_sum_f(sl);
    sn = wave_sum_f(sn);
    np = wave_sum_i(np);
    if (lane == 63) { redf[wid] = sn; redf2[wid] = sl; redi[wid] = np; }
    __syncthreads();
    if (tid == 0) {
        const float fN = (float)(redi[0] + redi[1] + redi[2] + redi[3]);
        out[0] = (redf2[0] + redf2[1] + redf2[2] + redf2[3]) / fN;
        out[1] = (redf[0] + redf[1] + redf[2] + redf[3]) / fN;
    }
}

extern "C" void kernel_launch(void* const* d_in, const int* in_sizes, int n_in,
                              void* d_out, int out_size, void* d_ws, size_t ws_size,
                              hipStream_t stream) {
    const float* conf = (const float*)d_in[0];
    const float* loc = (const float*)d_in[1];
    const float* priors = (const float*)d_in[2];
    const float* labels = (const float*)d_in[3];
    const int* objc = (const int*)d_in[4];
    float* out = (float*)d_out;

    // ws layout: sbp_g[3200] | part_loc/nll/np[2240 each] | negsum[64] |
    //            fix_np[64] | fix_nll[64] | fix_loc[64] | lc[Bn*Pn] | done
    int* sbp_g = (int*)d_ws;
    float* part_loc = (float*)(sbp_g + Bn * NMAXn);
    float* part_nll = part_loc + Bn * PX;
    int* part_np = (int*)(part_nll + Bn * PX);
    float* negsum = (float*)(part_np + Bn * PX);
    int* fix_np = (int*)(negsum + Bn);
    float* fix_nll = (float*)(fix_np + Bn);
    float* fix_loc = fix_nll + Bn;
    float* lc = fix_loc + Bn;
    int* done = (int*)(lc + (size_t)Bn * Pn);

    k_fused<<<Bn * PX + Bn * NMAXn, 256, 0, stream>>>(conf, loc, priors, labels, objc,
                                                      lc, part_loc, part_nll, part_np,
                                                      sbp_g);
    k_fix<<<Bn, 64, 0, stream>>>(conf, loc, priors, labels, objc, sbp_g, lc,
                                 fix_np, fix_nll, fix_loc, done);
    k_neg<<<Bn, 256, 0, stream>>>(lc, part_loc, part_nll, part_np,
                                  fix_np, fix_nll, fix_loc, negsum, done, out);
}

// Round 14
// 70.287 us; speedup vs baseline: 1.2052x; 1.0774x over previous
//
#include <hip/hip_runtime.h>
#include <math.h>

#define Bn 64
#define Pn 8732
#define Cn 21
#define NMAXn 50
#define PX 35  // ceil(Pn/256)

// ---------------- DPP wave64 reduces (VALU pipe, not LDS) -------------------
template <int C>
__device__ __forceinline__ float dppf(float x) {
    return __int_as_float(__builtin_amdgcn_update_dpp(0, __float_as_int(x), C, 0xf, 0xf, true));
}
template <int C>
__device__ __forceinline__ int dppi(int x) {
    return __builtin_amdgcn_update_dpp(0, x, C, 0xf, 0xf, true);
}
__device__ __forceinline__ float wave_sum_f(float x) {
    x += dppf<0x111>(x); x += dppf<0x112>(x); x += dppf<0x114>(x);
    x += dppf<0x118>(x); x += dppf<0x142>(x); x += dppf<0x143>(x);
    return x;  // lane 63
}
__device__ __forceinline__ int wave_sum_i(int x) {
    x += dppi<0x111>(x); x += dppi<0x112>(x); x += dppi<0x114>(x);
    x += dppi<0x118>(x); x += dppi<0x142>(x); x += dppi<0x143>(x);
    return x;  // lane 63
}

__device__ __forceinline__ float smoothl1_enc(const float4 l, const float4 pr,
                                              float gx0, float gy0, float gx1, float gy1) {
    const float tx = ((gx0 + gx1) * 0.5f - pr.x) / (0.1f * pr.z);
    const float ty = ((gy0 + gy1) * 0.5f - pr.y) / (0.1f * pr.w);
    const float tw = __logf((gx1 - gx0) / pr.z) * 5.0f;  // /0.2
    const float th = __logf((gy1 - gy0) / pr.w) * 5.0f;
    float s = 0.0f, d;
    d = fabsf(l.x - tx); s += (d < 1.0f) ? 0.5f * d * d : d - 0.5f;
    d = fabsf(l.y - ty); s += (d < 1.0f) ? 0.5f * d * d : d - 0.5f;
    d = fabsf(l.z - tw); s += (d < 1.0f) ? 0.5f * d * d : d - 0.5f;
    d = fabsf(l.w - th); s += (d < 1.0f) ? 0.5f * d * d : d - 0.5f;
    return s;
}

// ---------------------------------------------------------------------------
// K1, two roles in one dispatch. DIVISION-FREE IoU argmax: track (I, U) of the
// incumbent; challenger n wins iff I_n*U_best > I_best*U_n (cross-mult; 2 mul
// + cmp + selects vs ~14-inst IEEE divide). Threshold q>=0.5 <=> 2I >= U.
// (I,U >= 0, U > 0; 0-vs-0 tie keeps first = reference argmax semantics.)
//  Role A (bx < Bn*PX): per-prior best-GT argmax + main body (lse/nll/
//    smooth-L1/lc/partials). Pure per-thread loop, zero cross-lane ops.
//  Role B (bx >= Bn*PX): block-per-(b,n) best-prior argmax; per-thread (I,U,p)
//    tracker over ~35 strided priors; one (I,U,p) shfl reduce at the end
//    (product tie -> min p); writes global winner sbp_g[b][n].
// ---------------------------------------------------------------------------
__global__ __launch_bounds__(256) void k_fused(const float* __restrict__ conf,
                                               const float* __restrict__ loc,
                                               const float* __restrict__ priors,
                                               const float* __restrict__ labels,
                                               const int* __restrict__ objc,
                                               float* __restrict__ lc,
                                               float* __restrict__ part_loc,
                                               float* __restrict__ part_nll,
                                               int* __restrict__ part_np,
                                               int* __restrict__ sbp_g) {
    const int bx = blockIdx.x;
    const int tid = threadIdx.x;
    const int lane = tid & 63, wid = tid >> 6;

    __shared__ float sconf[256 * Cn];  // 21504 B (role A)
    __shared__ float lab[NMAXn * 5];
    __shared__ float rl[4], rn[4];
    __shared__ int rp[4];
    __shared__ float wkI[4], wkU[4];   // role B
    __shared__ int wkP[4];

    if (bx < Bn * PX) {
        // ================= Role A: match + main =================
        const int b = bx / PX;
        const int px = bx % PX;
        const int p0 = px * 256;
        const int rows = min(256, Pn - p0);
        const int cnt = objc[b];                  // uniform -> scalar
        const float* lb = labels + b * NMAXn * 5;

        const float4* src = reinterpret_cast<const float4*>(conf + ((size_t)b * Pn + p0) * Cn);
        const int n4 = rows * Cn / 4;  // rows*21 divisible by 4 for rows in {256,28}
        for (int i = tid; i < n4; i += 256) reinterpret_cast<float4*>(sconf)[i] = src[i];
        for (int i = tid; i < NMAXn * 5; i += 256) lab[i] = labels[b * NMAXn * 5 + i];

        const int p = p0 + tid;
        const int pcl = (p < Pn) ? p : (Pn - 1);
        const float4 pr = reinterpret_cast<const float4*>(priors)[pcl];
        const float px0 = pr.x - 0.5f * pr.z, py0 = pr.y - 0.5f * pr.w;
        const float px1 = pr.x + 0.5f * pr.z, py1 = pr.y + 0.5f * pr.w;
        const float parea = (px1 - px0) * (py1 - py0);
        float bI = 0.0f, bU = 1.0f;   // incumbent (I,U); n=0 always beats (0,1) unless I0==0 tie -> keep idx 0 anyway
        int bidx = 0;
        {   // n = 0 (cnt >= 1 guaranteed)
            const float gx0 = lb[0], gy0 = lb[1], gx1 = lb[2], gy1 = lb[3];
            const float lx = fmaxf(gx0, px0), ly = fmaxf(gy0, py0);
            const float rx = fminf(gx1, px1), ry = fminf(gy1, py1);
            const float w = fmaxf(rx - lx, 0.0f), h = fmaxf(ry - ly, 0.0f);
            bI = w * h;
            bU = (gx1 - gx0) * (gy1 - gy0) + parea - bI;
        }
        for (int n = 1; n < cnt; ++n) {   // pure per-thread; division-free
            const float gx0 = lb[n * 5 + 0], gy0 = lb[n * 5 + 1];
            const float gx1 = lb[n * 5 + 2], gy1 = lb[n * 5 + 3];
            const float lx = fmaxf(gx0, px0), ly = fmaxf(gy0, py0);
            const float rx = fminf(gx1, px1), ry = fminf(gy1, py1);
            const float w = fmaxf(rx - lx, 0.0f), h = fmaxf(ry - ly, 0.0f);
            const float I = w * h;
            const float U = (gx1 - gx0) * (gy1 - gy0) + parea - I;
            if (I * bU > bI * U) { bI = I; bU = U; bidx = n; }  // strict >: first occurrence
        }
        __syncthreads();  // sconf, lab ready

        float my_loc = 0.0f, my_nll = 0.0f;
        int my_np = 0;
        if (tid < rows) {
            const size_t gi = (size_t)b * Pn + p;
            const int ct = (2.0f * bI >= bU) ? ((int)lab[bidx * 5 + 4] + 1) : 0;
            const float* row = sconf + tid * Cn;  // stride 21: odd -> conflict-benign
            float m = row[0];
#pragma unroll
            for (int j = 1; j < Cn; ++j) m = fmaxf(m, row[j]);
            float s2 = 0.0f;
#pragma unroll
            for (int j = 0; j < Cn; ++j) s2 += __expf(row[j] - m);
            const float nll = __logf(s2) + m - row[ct];
            if (ct > 0) {
                lc[gi] = 0.0f;
                my_np = 1;
                my_nll = nll;
                const float4 l = reinterpret_cast<const float4*>(loc)[gi];
                my_loc = smoothl1_enc(l, pr, lab[bidx * 5 + 0], lab[bidx * 5 + 1],
                                      lab[bidx * 5 + 2], lab[bidx * 5 + 3]);
            } else {
                lc[gi] = nll;
            }
        }
        my_loc = wave_sum_f(my_loc);
        my_nll = wave_sum_f(my_nll);
        my_np = wave_sum_i(my_np);
        if (lane == 63) { rl[wid] = my_loc; rn[wid] = my_nll; rp[wid] = my_np; }
        __syncthreads();
        if (tid == 0) {
            const int g = b * PX + px;
            part_loc[g] = rl[0] + rl[1] + rl[2] + rl[3];
            part_nll[g] = rn[0] + rn[1] + rn[2] + rn[3];
            part_np[g] = rp[0] + rp[1] + rp[2] + rp[3];
        }
    } else {
        // ================= Role B: block-per-GT best-prior =================
        const int idx = bx - Bn * PX;
        const int b = idx / NMAXn;
        const int n = idx % NMAXn;
        if (n >= objc[b]) return;  // uniform per block
        const float* lbp = labels + (b * NMAXn + n) * 5;
        const float gx0 = lbp[0], gy0 = lbp[1], gx1 = lbp[2], gy1 = lbp[3];
        const float ga = (gx1 - gx0) * (gy1 - gy0);
        float bI, bU;
        int bp_;
        {   // j = 0 always valid (tid < 256 <= Pn)
            const float4 pr = reinterpret_cast<const float4*>(priors)[tid];
            const float px0 = pr.x - 0.5f * pr.z, py0 = pr.y - 0.5f * pr.w;
            const float px1 = pr.x + 0.5f * pr.z, py1 = pr.y + 0.5f * pr.w;
            const float lx = fmaxf(gx0, px0), ly = fmaxf(gy0, py0);
            const float rx = fminf(gx1, px1), ry = fminf(gy1, py1);
            const float w = fmaxf(rx - lx, 0.0f), h = fmaxf(ry - ly, 0.0f);
            bI = w * h;
            bU = ga + (px1 - px0) * (py1 - py0) - bI;
            bp_ = tid;
        }
        for (int j = 1; j < PX; ++j) {           // ascending p in-thread: > keeps min p
            const int p = tid + 256 * j;
            if (p < Pn) {
                const float4 pr = reinterpret_cast<const float4*>(priors)[p];
                const float px0 = pr.x - 0.5f * pr.z, py0 = pr.y - 0.5f * pr.w;
                const float px1 = pr.x + 0.5f * pr.z, py1 = pr.y + 0.5f * pr.w;
                const float lx = fmaxf(gx0, px0), ly = fmaxf(gy0, py0);
                const float rx = fminf(gx1, px1), ry = fminf(gy1, py1);
                const float w = fmaxf(rx - lx, 0.0f), h = fmaxf(ry - ly, 0.0f);
                const float I = w * h;
                const float U = ga + (px1 - px0) * (py1 - py0) - I;
                if (I * bU > bI * U) { bI = I; bU = U; bp_ = p; }
            }
        }
        // wave reduce of (I,U,p): product comparison, tie -> min p
        for (int off = 32; off > 0; off >>= 1) {
            const float oI = __shfl_down(bI, off);
            const float oU = __shfl_down(bU, off);
            const int op = __shfl_down(bp_, off);
            const float a = oI * bU, c = bI * oU;
            if (a > c || (a == c && op < bp_)) { bI = oI; bU = oU; bp_ = op; }
        }
        if (lane == 0) { wkI[wid] = bI; wkU[wid] = bU; wkP[wid] = bp_; }
        __syncthreads();
        if (tid == 0) {
            float cI = wkI[0], cU = wkU[0];
            int cp = wkP[0];
#pragma unroll
            for (int w = 1; w < 4; ++w) {
                const float a = wkI[w] * cU, c = cI * wkU[w];
                if (a > c || (a == c && wkP[w] < cp)) { cI = wkI[w]; cU = wkU[w]; cp = wkP[w]; }
            }
            sbp_g[b * NMAXn + n] = cp;
        }
    }
}

// ---------------------------------------------------------------------------
// K2 fixup (one wave per batch): stage sbp from global; last-n-wins; for each
// winning forced (n -> pp): recompute the OLD local match with the SAME
// cross-mult comparator, emit deltas (nll/loc/np), write lc[pp]=0.
// Resets done counter.
// ---------------------------------------------------------------------------
__global__ __launch_bounds__(64) void k_fix(const float* __restrict__ conf,
                                            const float* __restrict__ loc,
                                            const float* __restrict__ priors,
                                            const float* __restrict__ labels,
                                            const int* __restrict__ objc,
                                            const int* __restrict__ sbp_g,
                                            float* __restrict__ lc,
                                            int* __restrict__ fix_np,
                                            float* __restrict__ fix_nll,
                                            float* __restrict__ fix_loc,
                                            int* __restrict__ done) {
    __shared__ int sbp[NMAXn];
    __shared__ float lab[NMAXn * 5];
    const int b = blockIdx.x;
    const int tid = threadIdx.x;  // one wave
    if (b == 0 && tid == 0) *done = 0;
    const int cnt = objc[b];
    for (int i = tid; i < NMAXn * 5; i += 64) lab[i] = labels[b * NMAXn * 5 + i];
    if (tid < cnt) sbp[tid] = sbp_g[b * NMAXn + tid];
    __syncthreads();
    bool win = false;
    if (tid < cnt) {
        const int myp = sbp[tid];
        win = true;
        for (int n2 = tid + 1; n2 < cnt; ++n2) win = win && (sbp[n2] != myp);  // last n wins
    }
    float dnll = 0.0f, dloc = 0.0f;
    int dnp = 0;
    if (win) {
        const int pp = sbp[tid];
        const float4 prf = reinterpret_cast<const float4*>(priors)[pp];
        const float qx0 = prf.x - 0.5f * prf.z, qy0 = prf.y - 0.5f * prf.w;
        const float qx1 = prf.x + 0.5f * prf.z, qy1 = prf.y + 0.5f * prf.w;
        const float qarea = (qx1 - qx0) * (qy1 - qy0);
        float bI = 0.0f, bU = 1.0f;
        int bidx2 = 0;
        {
            const float gx0 = lab[0], gy0 = lab[1], gx1 = lab[2], gy1 = lab[3];
            const float lx = fmaxf(gx0, qx0), ly = fmaxf(gy0, qy0);
            const float rx = fminf(gx1, qx1), ry = fminf(gy1, qy1);
            const float w = fmaxf(rx - lx, 0.0f), h = fmaxf(ry - ly, 0.0f);
            bI = w * h;
            bU = (gx1 - gx0) * (gy1 - gy0) + qarea - bI;
        }
        for (int n2 = 1; n2 < cnt; ++n2) {
            const float gx0 = lab[n2 * 5 + 0], gy0 = lab[n2 * 5 + 1];
            const float gx1 = lab[n2 * 5 + 2], gy1 = lab[n2 * 5 + 3];
            const float lx = fmaxf(gx0, qx0), ly = fmaxf(gy0, qy0);
            const float rx = fminf(gx1, qx1), ry = fminf(gy1, qy1);
            const float w = fmaxf(rx - lx, 0.0f), h = fmaxf(ry - ly, 0.0f);
            const float I = w * h;
            const float U = (gx1 - gx0) * (gy1 - gy0) + qarea - I;
            if (I * bU > bI * U) { bI = I; bU = U; bidx2 = n2; }
        }
        const float* rowg = conf + ((size_t)b * Pn + pp) * Cn;
        float m2 = rowg[0];
#pragma unroll
        for (int j = 1; j < Cn; ++j) m2 = fmaxf(m2, rowg[j]);
        float ss = 0.0f;
#pragma unroll
        for (int j = 0; j < Cn; ++j) ss += __expf(rowg[j] - m2);
        const float lse = __logf(ss) + m2;
        const int ctn = (int)lab[tid * 5 + 4] + 1;
        const float4 lv = reinterpret_cast<const float4*>(loc)[(size_t)b * Pn + pp];
        dnll = lse - rowg[ctn];
        dloc = smoothl1_enc(lv, prf, lab[tid * 5 + 0], lab[tid * 5 + 1],
                            lab[tid * 5 + 2], lab[tid * 5 + 3]);
        dnp = 1;
        if (2.0f * bI >= bU) {  // old was positive: subtract its old contribution
            const int cto = (int)lab[bidx2 * 5 + 4] + 1;
            dnll -= (lse - rowg[cto]);
            dloc -= smoothl1_enc(lv, prf, lab[bidx2 * 5 + 0], lab[bidx2 * 5 + 1],
                                 lab[bidx2 * 5 + 2], lab[bidx2 * 5 + 3]);
            dnp = 0;
        }
        lc[(size_t)b * Pn + pp] = 0.0f;  // forced => positive => not a mining candidate
    }
    dnll = wave_sum_f(dnll);
    dloc = wave_sum_f(dloc);
    dnp = wave_sum_i(dnp);
    if (tid == 63) {
        fix_nll[b] = dnll;
        fix_loc[b] = dloc;
        fix_np[b] = dnp;
    }
}

// ---------------------------------------------------------------------------
// K3: per-batch hard-negative top-k sum. 256 threads x 12 float4 in registers;
// 31-iter bisection on float bits (exact); DPP reduces + 4-slot LDS combine;
// fused final reduce (adds fix_* deltas) via done counter.
// ---------------------------------------------------------------------------
__global__ __launch_bounds__(256) void k_neg(const float* __restrict__ lc,
                                             const float* __restrict__ part_loc,
                                             const float* __restrict__ part_nll,
                                             const int* __restrict__ part_np,
                                             const int* __restrict__ fix_np,
                                             const float* __restrict__ fix_nll,
                                             const float* __restrict__ fix_loc,
                                             float* __restrict__ negsum,
                                             int* __restrict__ done,
                                             float* __restrict__ out) {
    const int b = blockIdx.x;
    const int tid = threadIdx.x;
    const int lane = tid & 63, wid = tid >> 6;
    __shared__ int redc[2][4];
    __shared__ float redf[4], redf2[4];
    __shared__ int redi[4];
    __shared__ int np_sh, islast;

    const int NV = Pn / 4;  // 2183 float4s exactly
    const float4* src = reinterpret_cast<const float4*>(lc + (size_t)b * Pn);
    const float4 sent = make_float4(-1.0f, -1.0f, -1.0f, -1.0f);
    float4 rr[12];
#pragma unroll
    for (int j = 0; j < 12; ++j) {
        const int i = tid + 256 * j;
        rr[j] = (i < NV) ? src[i] : sent;
    }

    if (tid < 64) {
        int npl = (tid < PX) ? part_np[b * PX + tid] : 0;
        npl = wave_sum_i(npl);
        if (tid == 63) np_sh = npl;
    }
    __syncthreads();
    const int k = min(3 * (np_sh + fix_np[b]), Pn - 1);

    unsigned lo = 0u, hi = 0x7F800000u;
#pragma unroll 1
    for (int it = 0; it < 31; ++it) {
        const unsigned mid = lo + ((hi - lo) >> 1);
        const float fm = __uint_as_float(mid);  // fm >= 0: sentinels never counted
        int c = 0;
#pragma unroll
        for (int j = 0; j < 12; ++j)
            c += (rr[j].x >= fm) + (rr[j].y >= fm) + (rr[j].z >= fm) + (rr[j].w >= fm);
        c = wave_sum_i(c);
        if (lane == 63) redc[it & 1][wid] = c;
        __syncthreads();
        const int tot = redc[it & 1][0] + redc[it & 1][1]
                      + redc[it & 1][2] + redc[it & 1][3];
        if (tot >= k) lo = mid;
        else hi = mid;
    }
    const float v = __uint_as_float(lo);  // exact k-th largest value

    float sm = 0.0f;
    int c = 0;
#pragma unroll
    for (int j = 0; j < 12; ++j) {
        if (rr[j].x > v) { sm += rr[j].x; ++c; }
        if (rr[j].y > v) { sm += rr[j].y; ++c; }
        if (rr[j].z > v) { sm += rr[j].z; ++c; }
        if (rr[j].w > v) { sm += rr[j].w; ++c; }
    }
    sm = wave_sum_f(sm);
    c = wave_sum_i(c);
    if (lane == 63) { redf[wid] = sm; redi[wid] = c; }
    __syncthreads();
    if (tid == 0) {
        const float st = redf[0] + redf[1] + redf[2] + redf[3];
        const int ct = redi[0] + redi[1] + redi[2] + redi[3];
        negsum[b] = st + (float)(k - ct) * v;  // exact tie handling at boundary
        __threadfence();
        islast = (atomicAdd(done, 1) == Bn - 1) ? 1 : 0;
    }
    __syncthreads();
    if (!islast) return;
    __threadfence();

    float sl = 0.0f, sn = 0.0f;
    int np = 0;
    for (int i = tid; i < Bn * PX; i += 256) {
        sl += part_loc[i];
        sn += part_nll[i];
        np += part_np[i];
    }
    if (tid < Bn) {
        sn += negsum[tid] + fix_nll[tid];
        sl += fix_loc[tid];
        np += fix_np[tid];
    }
    sl = wave_sum_f(sl);
    sn = wave_sum_f(sn);
    np = wave_sum_i(np);
    if (lane == 63) { redf[wid] = sn; redf2[wid] = sl; redi[wid] = np; }
    __syncthreads();
    if (tid == 0) {
        const float fN = (float)(redi[0] + redi[1] + redi[2] + redi[3]);
        out[0] = (redf2[0] + redf2[1] + redf2[2] + redf2[3]) / fN;
        out[1] = (redf[0] + redf[1] + redf[2] + redf[3]) / fN;
    }
}

extern "C" void kernel_launch(void* const* d_in, const int* in_sizes, int n_in,
                              void* d_out, int out_size, void* d_ws, size_t ws_size,
                              hipStream_t stream) {
    const float* conf = (const float*)d_in[0];
    const float* loc = (const float*)d_in[1];
    const float* priors = (const float*)d_in[2];
    const float* labels = (const float*)d_in[3];
    const int* objc = (const int*)d_in[4];
    float* out = (float*)d_out;

    // ws layout: sbp_g[3200] | part_loc/nll/np[2240 each] | negsum[64] |
    //            fix_np[64] | fix_nll[64] | fix_loc[64] | lc[Bn*Pn] | done
    int* sbp_g = (int*)d_ws;
    float* part_loc = (float*)(sbp_g + Bn * NMAXn);
    float* part_nll = part_loc + Bn * PX;
    int* part_np = (int*)(part_nll + Bn * PX);
    float* negsum = (float*)(part_np + Bn * PX);
    int* fix_np = (int*)(negsum + Bn);
    float* fix_nll = (float*)(fix_np + Bn);
    float* fix_loc = fix_nll + Bn;
    float* lc = fix_loc + Bn;
    int* done = (int*)(lc + (size_t)Bn * Pn);

    k_fused<<<Bn * PX + Bn * NMAXn, 256, 0, stream>>>(conf, loc, priors, labels, objc,
                                                      lc, part_loc, part_nll, part_np,
                                                      sbp_g);
    k_fix<<<Bn, 64, 0, stream>>>(conf, loc, priors, labels, objc, sbp_g, lc,
                                 fix_np, fix_nll, fix_loc, done);
    k_neg<<<Bn, 256, 0, stream>>>(lc, part_loc, part_nll, part_np,
                                  fix_np, fix_nll, fix_loc, negsum, done, out);
}